// Round 10
// baseline (151.357 us; speedup 1.0000x reference)
//
#include <hip/hip_runtime.h>
#include <hip/hip_fp16.h>
#include <math.h>

#define HH 180
#define WW 180
#define BATCH 8
#define NF 24
#define NCP (NF / 2)            // 12 channel pairs
#define NB 31
#define HW (HH * WW)
#define NTOT (BATCH * HW)
#define NBLK 720                // 6 x 15 x 8 grid
#define SLICE 90                // float4s per block for the M reduction (64800/720)

// f32 PWL node table of phi over [-1.5, 1.5], step 1/512 (1537 nodes, built per-block)
#define TABN 1537
#define TAB_SCALE 512.0f
#define TAB_OFF 768.0f
#define RBF_L (-50.0f * 1.4426950408889634f)   // exp(-50 d^2) = exp2(RBF_L d^2)

#if __has_builtin(__builtin_amdgcn_exp2f)
#define EXP2(x) __builtin_amdgcn_exp2f(x)
#else
#define EXP2(x) __expf((x) * 0.6931471805599453f)
#endif

typedef float v2f __attribute__((ext_vector_type(2)));
static __device__ __forceinline__ v2f splat2(float x) { v2f r; r.x = x; r.y = x; return r; }

#define TX 32
#define TY 12
#define TW 36           // t-region 36x16 (halo 2)
#define TH 16
#define TPTS (TW * TH)  // 576
#define UW 40           // u-region 40x20 (halo 4)
#define UH 20

// Single fused kernel. M-dependency deferred to the epilogue via a device-scope
// partials handshake: every block release-stores its slice partial BEFORE any
// block spin-acquires them (spin sits after phase A). Poison 0xAA as float is
// -1.5e-13, real partials are >= ~100, so (pv > 0.5f) is an unambiguous flag.
// Co-residency: LDS ~37.0 KB + launch_bounds(256,4) -> >=3 blocks/CU -> >=768
// resident blocks >= 720 grid, so the spin cannot deadlock.
__global__ __launch_bounds__(256, 4) void tnrd_fused(const float* __restrict__ u,
                                                      const float* __restrict__ f,
                                                      const float* __restrict__ filters,
                                                      const float* __restrict__ lam_p,
                                                      const float* __restrict__ wts,
                                                      float* __restrict__ partials,
                                                      float* __restrict__ out) {
    __shared__ __align__(16) float su[UH * UW];           // 3.2 KB
    __shared__ __align__(16) unsigned st[NCP * TPTS];     // 27.65 KB (half2 {chA,chB})
    __shared__ __align__(16) float stab[TABN + 3];        // 6.16 KB f32 phi nodes
    __shared__ float sred[4];
    __shared__ float sM[1];

    int tid = threadIdx.x;
    int b = blockIdx.z;
    int x0 = blockIdx.x * TX, y0 = blockIdx.y * TY;
    int bid = blockIdx.x + 6 * (blockIdx.y + 15 * blockIdx.z);   // 0..719

    // (1) issue the M-slice load first (result needed soonest)
    float4 sl = make_float4(0.f, 0.f, 0.f, 0.f);
    if (tid < SLICE) sl = ((const float4*)u)[bid * SLICE + tid];

    // (2) stage u tile (origin y0-4, x0-4), zero-padded
    for (int e = tid; e < UH * UW; e += 256) {
        int r = e / UW, c = e - r * UW;
        int gy = y0 - 4 + r, gx = x0 - 4 + c;
        float v = 0.f;
        if (gy >= 0 && gy < HH && gx >= 0 && gx < WW) v = u[b * HW + gy * WW + gx];
        su[e] = v;
    }

    // (3) build f32 phi node table in LDS — pure VALU, overlaps load latency.
    //     No register array for weights (r8 spill lesson): wts[j] are uniform s_loads.
    for (int e = tid; e < TABN; e += 256) {
        float x = -1.5f + (float)e * (1.f / TAB_SCALE);
        float va = 0.f;
        #pragma unroll
        for (int j = 0; j < NB; j++) {
            float muj = -1.f + (float)j * (1.f / 15.f);
            float d = x - muj;
            va = fmaf(wts[j], EXP2(RBF_L * d * d), va);
        }
        stab[e] = va;
    }

    // (4) finish slice partial: weighted sum (cy*cx, 2 at border else 3)
    float v = 0.f;
    if (tid < SLICE) {
        int i4 = bid * SLICE + tid;
        int rem = (i4 * 4) % HW;            // multiple of 4
        int y = rem / WW, xr = rem % WW;
        float cy = (y == 0 || y == HH - 1) ? 2.f : 3.f;
        float c0 = (xr == 0) ? 2.f : 3.f;
        float c3 = (xr + 3 == WW - 1) ? 2.f : 3.f;
        v = cy * (sl.x * c0 + (sl.y + sl.z) * 3.f + sl.w * c3);
    }
    #pragma unroll
    for (int off = 32; off; off >>= 1) v += __shfl_down(v, off, 64);
    int lane = tid & 63, wid = tid >> 6;
    if (lane == 0) sred[wid] = v;
    __syncthreads();                                   // barrier 1 (covers su/stab too)
    if (tid == 0) {
        float tot = sred[0] + sred[1] + sred[2] + sred[3];
        __hip_atomic_store(&partials[bid], tot, __ATOMIC_RELEASE, __HIP_MEMORY_SCOPE_AGENT);
    }

    // ---- phase A: 432 items = 144 quads x 3 groups of 4 channel-pairs (no M needed) ----
    for (int it = tid; it < 432; it += 256) {
        int quad = it % 144, grp = it / 144;
        int r = quad / 9, cq = (quad - r * 9) * 4;     // TW/4 = 9
        float w[5][8];
        #pragma unroll
        for (int dy = 0; dy < 5; dy++) {
            float4 a = *(const float4*)&su[(r + dy) * UW + cq];
            float4 bb = *(const float4*)&su[(r + dy) * UW + cq + 4];
            w[dy][0] = a.x; w[dy][1] = a.y; w[dy][2] = a.z; w[dy][3] = a.w;
            w[dy][4] = bb.x; w[dy][5] = bb.y; w[dy][6] = bb.z; w[dy][7] = bb.w;
        }
        float S[6];
        #pragma unroll
        for (int m = 0; m < 6; m++) S[m] = w[1][m + 1] + w[2][m + 1] + w[3][m + 1];
        float us[4];
        int gy = y0 - 2 + r;
        bool okY = (gy >= 0 && gy < HH);
        #pragma unroll
        for (int p = 0; p < 4; p++) {
            us[p] = (S[p] + S[p + 1] + S[p + 2]) * (1.f / 9.f);
            int gx = x0 - 2 + cq + p;
            if (!(okY && gx >= 0 && gx < WW)) us[p] = 0.f;   // zero-pad t
        }
        #pragma unroll
        for (int cpi = 0; cpi < 4; cpi++) {
            int cp = grp * 4 + cpi;
            const float* fA = filters + (2 * cp) * 25;       // uniform s_loads
            const float* fB = fA + 25;
            v2f c2[4];
            #pragma unroll
            for (int p = 0; p < 4; p++) { c2[p].x = 0.f; c2[p].y = 0.f; }
            #pragma unroll
            for (int k = 0; k < 25; k++) {
                int dy = k / 5, dx = k - dy * 5;
                v2f fc; fc.x = fA[k]; fc.y = fB[k];
                #pragma unroll
                for (int p = 0; p < 4; p++)
                    c2[p] = __builtin_elementwise_fma(splat2(w[dy][dx + p]), fc, c2[p]);
            }
            uint4 pk;
            unsigned* pkp = (unsigned*)&pk;
            #pragma unroll
            for (int p = 0; p < 4; p++) {
                float tpA = fmaf(c2[p].x, TAB_SCALE, TAB_OFF);
                tpA = fminf(fmaxf(tpA, 0.f), 1535.f);
                int iA = (int)tpA; float frA = tpA - (float)iA;
                float a0 = stab[iA], a1 = stab[iA + 1];
                float vA = us[p] * fmaf(frA, a1 - a0, a0);
                float tpB = fmaf(c2[p].y, TAB_SCALE, TAB_OFF);
                tpB = fminf(fmaxf(tpB, 0.f), 1535.f);
                int iB = (int)tpB; float frB = tpB - (float)iB;
                float b0 = stab[iB], b1 = stab[iB + 1];
                float vB = us[p] * fmaf(frB, b1 - b0, b0);
                __half2 h = __floats2half2_rn(vA, vB);
                pkp[p] = *(unsigned*)&h;
            }
            *(uint4*)&st[cp * TPTS + r * TW + cq] = pk;      // 16B aligned
        }
    }
    __syncthreads();                                   // barrier 2

    // ---- M handshake: spin-acquire all 720 partials (all were written pre-phase-A) ----
    {
        float psum = 0.f;
        for (int s = tid; s < NBLK; s += 256) {
            float pv;
            do {
                pv = __hip_atomic_load(&partials[s], __ATOMIC_ACQUIRE, __HIP_MEMORY_SCOPE_AGENT);
            } while (!(pv > 0.5f));
            psum += pv;
        }
        #pragma unroll
        for (int off = 32; off; off >>= 1) psum += __shfl_down(psum, off, 64);
        if (lane == 0) sred[wid] = psum;
        __syncthreads();                               // barrier 3
        if (tid == 0)
            sM[0] = 1.0f / ((sred[0] + sred[1] + sred[2] + sred[3]) * (1.f / (9.f * (float)NTOT)) + 0.001f);
        __syncthreads();                               // barrier 4
    }

    // ---- phase B: adjoint conv, f16 pk-fma; fc built inline from uniform filter s_loads ----
    int txl = tid & 15, tyl = tid >> 4;
    int x = 2 * txl;                                         // 0..30
    if (tyl < TY) {
        float accf0 = 0.f, accf1 = 0.f;
        #pragma unroll 2
        for (int cp = 0; cp < NCP; cp++) {
            const float* fA = filters + (2 * cp) * 25;       // uniform s_loads
            const float* fB = fA + 25;
            __half2 a0 = __floats2half2_rn(0.f, 0.f);
            __half2 a1 = a0;
            #pragma unroll
            for (int ey = 0; ey < 5; ey++) {
                int base = cp * TPTS + (tyl + 4 - ey) * TW + x;   // even -> 8B aligned
                uint2 q0 = *(const uint2*)&st[base];
                uint2 q1 = *(const uint2*)&st[base + 2];
                uint2 q2 = *(const uint2*)&st[base + 4];
                unsigned hv[6] = {q0.x, q0.y, q1.x, q1.y, q2.x, q2.y};
                __half2 tc[6];
                #pragma unroll
                for (int j = 0; j < 6; j++) tc[j] = *(const __half2*)&hv[j];
                #pragma unroll
                for (int ex = 0; ex < 5; ex++) {
                    int q = ey * 5 + ex;
                    __half2 fc = __floats2half2_rn(fA[q], fB[q]);
                    a0 = __hfma2(tc[4 - ex], fc, a0);        // v_pk_fma_f16
                    a1 = __hfma2(tc[5 - ex], fc, a1);
                }
            }
            float2 p0 = __half22float2(a0), p1 = __half22float2(a1);
            accf0 += p0.x + p0.y;
            accf1 += p1.x + p1.y;
        }
        int gx = x0 + x, gyy = y0 + tyl;
        if (gx < WW && gyy < HH) {
            float invM = sM[0];
            float lam = lam_p[0];
            int gidx = b * HW + gyy * WW + gx;
            float d0 = accf0 * invM;
            float d1 = accf1 * invM;
            float2 f2 = *(const float2*)&f[gidx];
            float u0 = su[(tyl + 4) * UW + (x + 4)];
            float u1 = su[(tyl + 4) * UW + (x + 5)];
            float2 o2;
            float val;
            val = u0 - d0 - lam * (u0 - f2.x) / (u0 * u0 + 1e-3f);
            o2.x = fminf(fmaxf(val, 0.f), 1.f);
            val = u1 - d1 - lam * (u1 - f2.y) / (u1 * u1 + 1e-3f);
            o2.y = fminf(fmaxf(val, 0.f), 1.f);
            *(float2*)&out[gidx] = o2;
        }
    }
}

extern "C" void kernel_launch(void* const* d_in, const int* in_sizes, int n_in,
                              void* d_out, int out_size, void* d_ws, size_t ws_size,
                              hipStream_t stream) {
    const float* u       = (const float*)d_in[0];
    const float* f       = (const float*)d_in[1];
    const float* filters = (const float*)d_in[2];
    const float* lam_p   = (const float*)d_in[3];
    // d_in[4] = mu: compile-time linspace, folded into constants
    const float* wts     = (const float*)d_in[5];
    float* out = (float*)d_out;

    float* partials = (float*)d_ws;   // 720 floats; poison 0xAA (< 0) acts as "not ready"

    dim3 g(6, 15, 8);                 // 720 blocks, co-resident at >=3 blocks/CU
    tnrd_fused<<<g, 256, 0, stream>>>(u, f, filters, lam_p, wts, partials, out);
}

// Round 11
// 86.560 us; speedup vs baseline: 1.7486x; 1.7486x over previous
//
#include <hip/hip_runtime.h>
#include <hip/hip_fp16.h>
#include <math.h>

#define HH 180
#define WW 180
#define BATCH 8
#define NF 24
#define NCP (NF / 2)            // 12 channel pairs
#define NB 31
#define HW (HH * WW)
#define NTOT (BATCH * HW)

// PWL table of phi over [-1.5, 1.5], step 1/512, stored half2 {v, dv}
#define TABN 1536
#define TAB_SCALE 512.0f
#define TAB_OFF 768.0f
#define L2E 1.4426950408889634f
#define RBF_L (-50.0f * L2E)

#if __has_builtin(__builtin_amdgcn_exp2f)
#define EXP2(x) __builtin_amdgcn_exp2f(x)
#else
#define EXP2(x) __expf((x) * 0.6931471805599453f)
#endif

typedef float v2f __attribute__((ext_vector_type(2)));

static __device__ __forceinline__ v2f splat2(float x) { v2f r; r.x = x; r.y = x; return r; }

// ---- K1: partials (blocks 0..127), table (128..133), fT2 + fTh (134) ----
__global__ __launch_bounds__(256) void k1_prepare(const float* __restrict__ u,
                                                  const float* __restrict__ wts,
                                                  const float* __restrict__ filters,
                                                  float* __restrict__ partials,
                                                  __half2* __restrict__ tab,
                                                  float* __restrict__ fT,
                                                  __half2* __restrict__ fTh) {
    __shared__ float sred[4];
    int blk = blockIdx.x, tid = threadIdx.x;
    if (blk < 128) {
        float v = 0.f;
        for (int i = blk * 256 + tid; i < NTOT / 4; i += 128 * 256) {
            float4 uv = ((const float4*)u)[i];
            int rem = (i * 4) % HW;
            int y = rem / WW, x0 = rem % WW;
            float cy = (y == 0 || y == HH - 1) ? 2.f : 3.f;
            float c0 = (x0 == 0) ? 2.f : 3.f;
            float c3 = (x0 + 3 == WW - 1) ? 2.f : 3.f;
            v += cy * (uv.x * c0 + (uv.y + uv.z) * 3.f + uv.w * c3);
        }
        #pragma unroll
        for (int off = 32; off; off >>= 1) v += __shfl_down(v, off, 64);
        int lane = tid & 63, wid = tid >> 6;
        if (lane == 0) sred[wid] = v;
        __syncthreads();
        if (tid == 0) partials[blk] = sred[0] + sred[1] + sred[2] + sred[3];
    } else if (blk < 134) {
        int e = (blk - 128) * 256 + tid;       // 0..1535
        float w[NB];
        #pragma unroll
        for (int j = 0; j < NB; j++) w[j] = wts[j];
        float xa = -1.5f + (float)e * (1.f / TAB_SCALE);
        float xb = xa + (1.f / TAB_SCALE);
        float va = 0.f, vb = 0.f;
        #pragma unroll
        for (int j = 0; j < NB; j++) {
            float muj = -1.f + (float)j * (1.f / 15.f);
            float da = xa - muj, db = xb - muj;
            va = fmaf(w[j], EXP2(RBF_L * da * da), va);
            vb = fmaf(w[j], EXP2(RBF_L * db * db), vb);
        }
        tab[e] = __floats2half2_rn(va, vb - va);
    } else {
        // fT[(cp*25+k)*2+s] = filters[(2cp+s)*25+k];  fTh = same pair as half2
        for (int e = tid; e < NCP * 25; e += 256) {   // 300 entries
            int cp = e / 25, k = e - cp * 25;
            float a = filters[(2 * cp) * 25 + k];
            float b = filters[(2 * cp + 1) * 25 + k];
            fT[2 * e] = a;
            fT[2 * e + 1] = b;
            fTh[e] = __floats2half2_rn(a, b);
        }
    }
}

// ---- K23: fused conv+RBF+adjoint; phase A fp32 pk balanced, phase B f16 pk b64 ----
// NOTE r11: __launch_bounds__(256) with NO min-waves arg. (256,4) made the
// compiler squeeze VGPRs to 64 (8-wave boundary) and spill ~11 KB/block to
// scratch (r8/r10 counters: VGPR=64 + inflated FETCH/WRITE) while LDS caps
// occupancy at 4 blocks/CU anyway. r3's plain (256) gave VGPR=112, no spill.
#define TX 32
#define TY 12
#define TW 36           // t-region 36x16 (halo 2)
#define TH 16
#define TPTS (TW * TH)  // 576
#define UW 40           // u-region 40x20 (halo 4)
#define UH 20

static __device__ __forceinline__ float phi_lut(const __half2* stab, float c) {
    float tp = fmaf(c, TAB_SCALE, TAB_OFF);
    tp = fminf(fmaxf(tp, 0.f), (float)(TABN - 1));
    int i = (int)tp;
    float fr = tp - (float)i;
    float2 e = __half22float2(stab[i]);
    return fmaf(fr, e.y, e.x);
}

__global__ __launch_bounds__(256) void k23_fused(const float* __restrict__ u,
                                                  const float* __restrict__ f,
                                                  const float* __restrict__ lam_p,
                                                  const float* __restrict__ partials,
                                                  const __half2* __restrict__ tab,
                                                  const v2f* __restrict__ fT2,
                                                  const __half2* __restrict__ fTh,
                                                  float* __restrict__ out) {
    __shared__ __align__(16) float su[UH * UW];           // 3.2 KB
    __shared__ __align__(16) unsigned st[NCP * TPTS];     // 27.6 KB (half2 {chA,chB})
    __shared__ __align__(16) __half2 stab[TABN];          // 6 KB
    __shared__ float sM[1];
    int b = blockIdx.z;
    int x0 = blockIdx.x * TX, y0 = blockIdx.y * TY;
    int tid = threadIdx.x;

    // stage u (origin y0-4, x0-4), zero-padded
    for (int e = tid; e < UH * UW; e += 256) {
        int r = e / UW, c = e - r * UW;
        int gy = y0 - 4 + r, gx = x0 - 4 + c;
        float v = 0.f;
        if (gy >= 0 && gy < HH && gx >= 0 && gx < WW) v = u[b * HW + gy * WW + gx];
        su[e] = v;
    }
    for (int e = tid; e < TABN / 4; e += 256)
        ((float4*)stab)[e] = ((const float4*)tab)[e];
    if (tid < 64) {
        float ps = partials[tid] + partials[tid + 64];
        #pragma unroll
        for (int off = 32; off; off >>= 1) ps += __shfl_down(ps, off, 64);
        if (tid == 0) sM[0] = 1.0f / (ps * (1.f / (9.f * (float)NTOT)) + 0.001f);
    }
    __syncthreads();

    // ---- phase A: 432 items = 144 quads x 3 groups of 4 channel-pairs ----
    for (int it = tid; it < 432; it += 256) {
        int quad = it % 144, grp = it / 144;              // grp 0..2
        int r = quad / 9, cq = (quad - r * 9) * 4;        // TW/4 = 9
        float w[5][8];
        #pragma unroll
        for (int dy = 0; dy < 5; dy++) {
            float4 a = *(const float4*)&su[(r + dy) * UW + cq];
            float4 bb = *(const float4*)&su[(r + dy) * UW + cq + 4];
            w[dy][0] = a.x; w[dy][1] = a.y; w[dy][2] = a.z; w[dy][3] = a.w;
            w[dy][4] = bb.x; w[dy][5] = bb.y; w[dy][6] = bb.z; w[dy][7] = bb.w;
        }
        float S[6];
        #pragma unroll
        for (int m = 0; m < 6; m++) S[m] = w[1][m + 1] + w[2][m + 1] + w[3][m + 1];
        float us[4];
        int gy = y0 - 2 + r;
        bool okY = (gy >= 0 && gy < HH);
        #pragma unroll
        for (int p = 0; p < 4; p++) {
            us[p] = (S[p] + S[p + 1] + S[p + 2]) * (1.f / 9.f);
            int gx = x0 - 2 + cq + p;
            if (!(okY && gx >= 0 && gx < WW)) us[p] = 0.f;   // zero-pad t
        }
        #pragma unroll
        for (int cpi = 0; cpi < 4; cpi++) {
            int cp = grp * 4 + cpi;
            v2f c2[4];
            #pragma unroll
            for (int p = 0; p < 4; p++) { c2[p].x = 0.f; c2[p].y = 0.f; }
            #pragma unroll
            for (int k = 0; k < 25; k++) {
                int dy = k / 5, dx = k - dy * 5;
                v2f fc = fT2[cp * 25 + k];                   // uniform -> s_load_dwordx2
                #pragma unroll
                for (int p = 0; p < 4; p++)
                    c2[p] = __builtin_elementwise_fma(splat2(w[dy][dx + p]), fc, c2[p]);
            }
            uint4 pk;
            unsigned* pkp = (unsigned*)&pk;
            #pragma unroll
            for (int p = 0; p < 4; p++) {
                float vA = us[p] * phi_lut(stab, c2[p].x);
                float vB = us[p] * phi_lut(stab, c2[p].y);
                __half2 h = __floats2half2_rn(vA, vB);
                pkp[p] = *(unsigned*)&h;
            }
            *(uint4*)&st[cp * TPTS + r * TW + cq] = pk;      // 16B aligned
        }
    }
    __syncthreads();

    // ---- phase B: adjoint conv, f16 pk-fma; per-ey b64 reads (low reg pressure) ----
    int txl = tid & 15, tyl = tid >> 4;
    int x = 2 * txl;                                         // 0..30
    if (tyl < TY) {
        float accf0 = 0.f, accf1 = 0.f;
        #pragma unroll 2
        for (int cp = 0; cp < NCP; cp++) {
            __half2 a0 = __floats2half2_rn(0.f, 0.f);
            __half2 a1 = a0;
            #pragma unroll
            for (int ey = 0; ey < 5; ey++) {
                int base = cp * TPTS + (tyl + 4 - ey) * TW + x;   // even -> 8B aligned
                uint2 q0 = *(const uint2*)&st[base];
                uint2 q1 = *(const uint2*)&st[base + 2];
                uint2 q2 = *(const uint2*)&st[base + 4];
                unsigned hv[6] = {q0.x, q0.y, q1.x, q1.y, q2.x, q2.y};
                __half2 tc[6];
                #pragma unroll
                for (int j = 0; j < 6; j++) tc[j] = *(const __half2*)&hv[j];
                #pragma unroll
                for (int ex = 0; ex < 5; ex++) {
                    __half2 fc = fTh[cp * 25 + ey * 5 + ex]; // uniform -> s_load_dword
                    a0 = __hfma2(tc[4 - ex], fc, a0);        // v_pk_fma_f16
                    a1 = __hfma2(tc[5 - ex], fc, a1);
                }
            }
            float2 p0 = __half22float2(a0), p1 = __half22float2(a1);
            accf0 += p0.x + p0.y;
            accf1 += p1.x + p1.y;
        }
        int gx = x0 + x, gyy = y0 + tyl;
        if (gx < WW && gyy < HH) {
            float invM = sM[0];
            float lam = lam_p[0];
            int gidx = b * HW + gyy * WW + gx;
            float d0 = accf0 * invM;
            float d1 = accf1 * invM;
            float2 f2 = *(const float2*)&f[gidx];
            float u0 = su[(tyl + 4) * UW + (x + 4)];
            float u1 = su[(tyl + 4) * UW + (x + 5)];
            float2 o2;
            float val;
            val = u0 - d0 - lam * (u0 - f2.x) / (u0 * u0 + 1e-3f);
            o2.x = fminf(fmaxf(val, 0.f), 1.f);
            val = u1 - d1 - lam * (u1 - f2.y) / (u1 * u1 + 1e-3f);
            o2.y = fminf(fmaxf(val, 0.f), 1.f);
            *(float2*)&out[gidx] = o2;
        }
    }
}

extern "C" void kernel_launch(void* const* d_in, const int* in_sizes, int n_in,
                              void* d_out, int out_size, void* d_ws, size_t ws_size,
                              hipStream_t stream) {
    const float* u       = (const float*)d_in[0];
    const float* f       = (const float*)d_in[1];
    const float* filters = (const float*)d_in[2];
    const float* lam_p   = (const float*)d_in[3];
    // d_in[4] = mu: compile-time linspace, folded into constants
    const float* wts     = (const float*)d_in[5];
    float* out = (float*)d_out;

    float*   partials = (float*)d_ws;                          // 128 floats
    __half2* tab      = (__half2*)((char*)d_ws + 1024);        // 1536 half2 = 6 KB
    float*   fT       = (float*)((char*)d_ws + 8192);          // 600 floats
    __half2* fTh      = (__half2*)((char*)d_ws + 12288);       // 300 half2

    k1_prepare<<<135, 256, 0, stream>>>(u, wts, filters, partials, tab, fT, fTh);

    dim3 g((WW + TX - 1) / TX, (HH + TY - 1) / TY, BATCH);     // 6 x 15 x 8 = 720
    k23_fused<<<g, 256, 0, stream>>>(u, f, lam_p, partials, tab, (const v2f*)fT, fTh, out);
}